// Round 10
// baseline (1382.663 us; speedup 1.0000x reference)
//
#include <hip/hip_runtime.h>
#include <stdint.h>

#define B_ 4
#define H_ 16
#define S_ 2048
#define D_ 64
#define NTH 512
#define NWAVES 8
#define QB 128                        /* q-rows per block (16 per wave) */
#define NWIN 64                       /* 32-k windows, full S */

typedef __attribute__((ext_vector_type(8))) short short8;
typedef __attribute__((ext_vector_type(4))) float float4v;
typedef __attribute__((ext_vector_type(4))) unsigned int uint4v;

static __device__ __forceinline__ short f2bf(float f) {
  uint32_t u = __builtin_bit_cast(uint32_t, f);
  u = (u + 0x7FFFu + ((u >> 16) & 1u)) >> 16;   // RNE
  return (short)u;
}
// packed f32x2 -> bf16x2 (RNE)
static __device__ __forceinline__ uint32_t cvtpk(float lo, float hi) {
  uint32_t r;
  asm("v_cvt_pk_bf16_f32 %0, %1, %2" : "=v"(r) : "v"(lo), "v"(hi));
  return r;
}
static __device__ __forceinline__ uint32_t nz4(uint32_t d) {
  uint32_t x = (d & 0x7F7F7F7Fu) + 0x7F7F7F7Fu;
  x = (x | d) & 0x80808080u;
  return x >> 7;
}
static __device__ __forceinline__ uint32_t nib(uint32_t d) {
  return ((nz4(d) * 0x01020408u) >> 24) & 0xFu;
}

#define KBF_OFF    ((size_t)64)
#define KBF_BYTES  ((size_t)B_ * H_ * S_ * D_ * 2)
#define VT_OFF     (KBF_OFF + KBF_BYTES)
#define VT_BYTES   ((size_t)B_ * H_ * S_ * D_ * 2)

__global__ void detect_mask_dtype(const uint8_t* __restrict__ m, uint32_t* flag) {
  uint32_t a = 0, b = 0;
  for (int i = threadIdx.x; i < 65536; i += 256) {
    uint8_t x = m[i];
    if (i & 3) a |= x; else b |= x;
  }
  uint32_t bits = (a ? 1u : 0u) | (b ? 2u : 0u);
  if (bits) atomicOr(flag, bits);
}

__global__ __launch_bounds__(256) void prep_k(const float* __restrict__ K,
                                              short* __restrict__ Kbf) {
  size_t base = ((size_t)blockIdx.x * 256 + threadIdx.x) * 8;
  float4v a = __builtin_nontemporal_load((const float4v*)(K + base));
  float4v b = __builtin_nontemporal_load((const float4v*)(K + base + 4));
  short8 o;
  o[0]=f2bf(a.x); o[1]=f2bf(a.y); o[2]=f2bf(a.z); o[3]=f2bf(a.w);
  o[4]=f2bf(b.x); o[5]=f2bf(b.y); o[6]=f2bf(b.z); o[7]=f2bf(b.w);
  *(short8*)(Kbf + base) = o;
}

__global__ __launch_bounds__(256) void prep_vt(const float* __restrict__ V,
                                               short* __restrict__ VT) {
  __shared__ short tile[64][72];
  int bh = blockIdx.x >> 5, k0 = (blockIdx.x & 31) * 64;
  const float* src = V + ((size_t)bh * S_ + k0) * D_;
  int t = threadIdx.x;
  int r = t >> 2, c0 = (t & 3) * 16;
#pragma unroll
  for (int j = 0; j < 4; ++j) {
    float4v f = __builtin_nontemporal_load((const float4v*)(src + (size_t)r * D_ + c0 + j * 4));
    tile[r][c0 + j*4 + 0] = f2bf(f.x);
    tile[r][c0 + j*4 + 1] = f2bf(f.y);
    tile[r][c0 + j*4 + 2] = f2bf(f.z);
    tile[r][c0 + j*4 + 3] = f2bf(f.w);
  }
  __syncthreads();
  int d = t >> 2, ks0 = (t & 3) * 16;
  short* dst = VT + (size_t)bh * D_ * S_ + (size_t)d * S_ + k0 + ks0;
#pragma unroll
  for (int half = 0; half < 2; ++half) {
    short8 o;
#pragma unroll
    for (int i = 0; i < 8; ++i) o[i] = tile[ks0 + half * 8 + i][d];
    *(short8*)(dst + half * 8) = o;
  }
}

template <int PREP>
__global__ __launch_bounds__(NTH, 4) void attn_fused(
    const float* __restrict__ Q, const float* __restrict__ K,
    const float* __restrict__ V, const float* __restrict__ scale_p,
    const uint8_t* __restrict__ M, const uint32_t* __restrict__ flag,
    const short* __restrict__ Kbf, const short* __restrict__ VT,
    float* __restrict__ outC, float* __restrict__ outA)
{
  __shared__ uint32_t mbits[QB * 65];           // 33.3 KB  (bit = masked)
  __shared__ float tiles[NWAVES][16 * 33];      // 16.9 KB  wave-private staging

  // XCD-chunked bijective swizzle: 1024 blocks = 8 XCDs x 128
  const int bx  = (blockIdx.x & 7) * 128 + (blockIdx.x >> 3);
  const int bh  = bx >> 4;                      // 16 q-tiles of 128 per (b,h)
  const int q0  = (bx & 15) * QB;

  const int tid  = threadIdx.x;
  const int w    = tid >> 6;
  const int lane = tid & 63;
  const int g    = lane >> 4;
  const int c    = lane & 15;
  const int qw   = q0 + w * 16;                 // wave's 16 q-rows

  const float scale = scale_p[0];
  const uint32_t fl = flag[0];

  // ---- mask bitmap prologue: [128][2048] bits, read once ----
  {
    const int row = tid >> 2;                   // 0..127
    const int wq0 = (tid & 3) * 16;             // 16 words each
    if (fl == 3u) {                             // byte mask
      const uint8_t* mrow = M + ((size_t)(bh * S_ + q0 + row)) * S_ + wq0 * 32;
#pragma unroll
      for (int j = 0; j < 16; ++j) {
        uint4v a = __builtin_nontemporal_load((const uint4v*)(mrow + j * 32));
        uint4v b = __builtin_nontemporal_load((const uint4v*)(mrow + j * 32 + 16));
        mbits[row * 65 + wq0 + j] =
            nib(a.x) | (nib(a.y) << 4) | (nib(a.z) << 8)  | (nib(a.w) << 12)
          | (nib(b.x) << 16) | (nib(b.y) << 20) | (nib(b.z) << 24) | (nib(b.w) << 28);
      }
    } else {                                    // 4-byte mask
      const uint32_t* mrow = (const uint32_t*)M + ((size_t)(bh * S_ + q0 + row)) * S_ + wq0 * 32;
#pragma unroll
      for (int j = 0; j < 16; ++j) {
        uint32_t bits = 0;
#pragma unroll
        for (int u = 0; u < 8; ++u) {
          uint4v wv = __builtin_nontemporal_load((const uint4v*)(mrow + j * 32 + u * 4));
          uint32_t nzb = (wv.x ? 1u : 0u) | (wv.y ? 2u : 0u) | (wv.z ? 4u : 0u) | (wv.w ? 8u : 0u);
          bits |= nzb << (u * 4);
        }
        mbits[row * 65 + wq0 + j] = bits;
      }
    }
  }
  __syncthreads();                              // ONLY barrier in the kernel

  // ---- Q as B-frag: lane holds Q[qw + c][.] ----
  short8 qB[2];
  {
    const float* qr = Q + ((size_t)(bh * S_ + qw + c)) * D_;
    float4v x0 = *(const float4v*)(qr + g * 8);
    float4v x1 = *(const float4v*)(qr + g * 8 + 4);
    float4v y0 = *(const float4v*)(qr + 32 + g * 8);
    float4v y1 = *(const float4v*)(qr + 32 + g * 8 + 4);
    short8 f;
    f[0]=f2bf(x0.x); f[1]=f2bf(x0.y); f[2]=f2bf(x0.z); f[3]=f2bf(x0.w);
    f[4]=f2bf(x1.x); f[5]=f2bf(x1.y); f[6]=f2bf(x1.z); f[7]=f2bf(x1.w);
    qB[0] = f;
    f[0]=f2bf(y0.x); f[1]=f2bf(y0.y); f[2]=f2bf(y0.z); f[3]=f2bf(y0.w);
    f[4]=f2bf(y1.x); f[5]=f2bf(y1.y); f[6]=f2bf(y1.z); f[7]=f2bf(y1.w);
    qB[1] = f;
  }

  const uint32_t* mrow = &mbits[(w * 16 + c) * 65];
  const short* Kbp = Kbf + (size_t)bh * S_ * D_;
  const short* VTp = VT + (size_t)bh * D_ * S_;
  const float* Kfp = K + (size_t)bh * S_ * D_;
  const float* Vfp = V + (size_t)bh * S_ * D_;

  // ---- sweep 1: row sums only ----
  float rs0 = 0.f, rs1 = 0.f;
#pragma unroll 4
  for (int win = 0; win < NWIN; ++win) {
    short8 a0, a1, a2, a3;
    if (PREP) {
      const short* kr = Kbp + (size_t)(win * 32 + c) * D_ + g * 8;
      const short* kr1 = kr + 16 * D_;
      a0 = *(const short8*)kr;  a1 = *(const short8*)(kr + 32);
      a2 = *(const short8*)kr1; a3 = *(const short8*)(kr1 + 32);
    } else {
      const float* kr = Kfp + (size_t)(win * 32 + c) * D_ + g * 8;
      const float* kr1 = kr + 16 * D_;
#pragma unroll
      for (int e = 0; e < 8; ++e) {
        a0[e] = f2bf(kr[e]);  a1[e] = f2bf(kr[32 + e]);
        a2[e] = f2bf(kr1[e]); a3[e] = f2bf(kr1[32 + e]);
      }
    }
    float4v acc0 = (float4v){0.f,0.f,0.f,0.f};
    float4v acc1 = (float4v){0.f,0.f,0.f,0.f};
    acc0 = __builtin_amdgcn_mfma_f32_16x16x32_bf16(a0, qB[0], acc0, 0, 0, 0);
    acc0 = __builtin_amdgcn_mfma_f32_16x16x32_bf16(a1, qB[1], acc0, 0, 0, 0);
    acc1 = __builtin_amdgcn_mfma_f32_16x16x32_bf16(a2, qB[0], acc1, 0, 0, 0);
    acc1 = __builtin_amdgcn_mfma_f32_16x16x32_bf16(a3, qB[1], acc1, 0, 0, 0);
    const uint32_t mw = mrow[win];
#pragma unroll
    for (int r = 0; r < 4; ++r) {
      rs0 += ((mw >> (4 * g + r)) & 1u)      ? 1.0f : __expf(acc0[r] * scale);
      rs1 += ((mw >> (16 + 4 * g + r)) & 1u) ? 1.0f : __expf(acc1[r] * scale);
    }
  }
  float rsv = rs0 + rs1;
  rsv += __shfl_xor(rsv, 16);
  rsv += __shfl_xor(rsv, 32);
  const float linvq = 1.0f / rsv;               // all lanes: 1/lsum for q = qw+c

  // ---- sweep 2: recompute, normalize, store full lines, PV ----
  float* tile = tiles[w];
  float4v cacc[4];
#pragma unroll
  for (int nd = 0; nd < 4; ++nd) cacc[nd] = (float4v){0.f, 0.f, 0.f, 0.f};
  const int rowA = lane >> 3;                   // store mapping: 8 rows/instr
  const int colq = (lane & 7) * 4;
  float* arow0 = outA + ((size_t)(bh * S_ + qw + rowA)) * S_;
  float* arow1 = outA + ((size_t)(bh * S_ + qw + rowA + 8)) * S_;

#pragma unroll 2
  for (int win = 0; win < NWIN; ++win) {
    short8 a0, a1, a2, a3, vA[4];
    if (PREP) {
      const short* kr = Kbp + (size_t)(win * 32 + c) * D_ + g * 8;
      const short* kr1 = kr + 16 * D_;
      a0 = *(const short8*)kr;  a1 = *(const short8*)(kr + 32);
      a2 = *(const short8*)kr1; a3 = *(const short8*)(kr1 + 32);
      const short* vb = VTp + (size_t)c * S_ + win * 32 + g * 8;
      vA[0] = *(const short8*)vb;
      vA[1] = *(const short8*)(vb + 16 * (size_t)S_);
      vA[2] = *(const short8*)(vb + 32 * (size_t)S_);
      vA[3] = *(const short8*)(vb + 48 * (size_t)S_);
    } else {
      const float* kr = Kfp + (size_t)(win * 32 + c) * D_ + g * 8;
      const float* kr1 = kr + 16 * D_;
#pragma unroll
      for (int e = 0; e < 8; ++e) {
        a0[e] = f2bf(kr[e]);  a1[e] = f2bf(kr[32 + e]);
        a2[e] = f2bf(kr1[e]); a3[e] = f2bf(kr1[32 + e]);
      }
#pragma unroll
      for (int nd = 0; nd < 4; ++nd) {
        const float* vc = Vfp + (size_t)(win * 32 + g * 8) * D_ + nd * 16 + c;
#pragma unroll
        for (int e = 0; e < 8; ++e) vA[nd][e] = f2bf(vc[(size_t)e * D_]);
      }
    }

    __builtin_amdgcn_s_setprio(1);
    float4v acc0 = (float4v){0.f,0.f,0.f,0.f};
    float4v acc1 = (float4v){0.f,0.f,0.f,0.f};
    acc0 = __builtin_amdgcn_mfma_f32_16x16x32_bf16(a0, qB[0], acc0, 0, 0, 0);
    acc0 = __builtin_amdgcn_mfma_f32_16x16x32_bf16(a1, qB[1], acc0, 0, 0, 0);
    acc1 = __builtin_amdgcn_mfma_f32_16x16x32_bf16(a2, qB[0], acc1, 0, 0, 0);
    acc1 = __builtin_amdgcn_mfma_f32_16x16x32_bf16(a3, qB[1], acc1, 0, 0, 0);
    __builtin_amdgcn_s_setprio(0);

    const uint32_t mw = mrow[win];
    float4v n0, n1;
#pragma unroll
    for (int r = 0; r < 4; ++r) {
      n0[r] = (((mw >> (4 * g + r)) & 1u)      ? 1.0f : __expf(acc0[r] * scale)) * linvq;
      n1[r] = (((mw >> (16 + 4 * g + r)) & 1u) ? 1.0f : __expf(acc1[r] * scale)) * linvq;
    }
    // normalized fp32 attention -> wave-private tile [q=c][k-offset]
    *(float4v*)&tile[c * 33 + 4 * g]      = n0;
    *(float4v*)&tile[c * 33 + 16 + 4 * g] = n1;
    asm volatile("s_waitcnt lgkmcnt(0)" ::: "memory");

    // PV B-frag from tile (bf16)
    float4v t0 = *(const float4v*)&tile[c * 33 + g * 8];
    float4v t1 = *(const float4v*)&tile[c * 33 + g * 8 + 4];
    uint4v bb;
    bb.x = cvtpk(t0.x, t0.y); bb.y = cvtpk(t0.z, t0.w);
    bb.z = cvtpk(t1.x, t1.y); bb.w = cvtpk(t1.z, t1.w);
    const short8 bfrag = __builtin_bit_cast(short8, bb);
    __builtin_amdgcn_s_setprio(1);
    cacc[0] = __builtin_amdgcn_mfma_f32_16x16x32_bf16(vA[0], bfrag, cacc[0], 0, 0, 0);
    cacc[1] = __builtin_amdgcn_mfma_f32_16x16x32_bf16(vA[1], bfrag, cacc[1], 0, 0, 0);
    cacc[2] = __builtin_amdgcn_mfma_f32_16x16x32_bf16(vA[2], bfrag, cacc[2], 0, 0, 0);
    cacc[3] = __builtin_amdgcn_mfma_f32_16x16x32_bf16(vA[3], bfrag, cacc[3], 0, 0, 0);
    __builtin_amdgcn_s_setprio(0);

    // full-128B-line stores: 8 rows per instruction
    float4v s0 = *(const float4v*)&tile[rowA * 33 + colq];
    float4v s1 = *(const float4v*)&tile[(rowA + 8) * 33 + colq];
    __builtin_nontemporal_store(s0, (float4v*)(arow0 + win * 32 + colq));
    __builtin_nontemporal_store(s1, (float4v*)(arow1 + win * 32 + colq));
    asm volatile("" ::: "memory");              // keep next win's tile writes behind reads
  }

  // ---- context write: cacc is final (normalized PV) ----
  {
    float* crow = outC + ((size_t)(bh * S_ + qw + c)) * D_;
#pragma unroll
    for (int nd = 0; nd < 4; ++nd)
      __builtin_nontemporal_store(cacc[nd], (float4v*)(crow + nd * 16 + 4 * g));
  }
}

extern "C" void kernel_launch(void* const* d_in, const int* in_sizes, int n_in,
                              void* d_out, int out_size, void* d_ws, size_t ws_size,
                              hipStream_t stream) {
  const float*   Q     = (const float*)d_in[0];
  const float*   K     = (const float*)d_in[1];
  const float*   V     = (const float*)d_in[2];
  const float*   scale = (const float*)d_in[3];
  const uint8_t* M     = (const uint8_t*)d_in[4];
  uint32_t* flag = (uint32_t*)d_ws;
  short* Kbf = (short*)((char*)d_ws + KBF_OFF);
  short* VT  = (short*)((char*)d_ws + VT_OFF);
  float* outC = (float*)d_out;
  float* outA = outC + (size_t)B_ * H_ * S_ * D_;

  hipMemsetAsync(flag, 0, 4, stream);
  detect_mask_dtype<<<dim3(1), dim3(256), 0, stream>>>(M, flag);

  const bool prep = ws_size >= VT_OFF + VT_BYTES;
  const int grid = B_ * H_ * (S_ / QB);         // 1024
  if (prep) {
    prep_k<<<dim3((B_ * H_ * S_ * D_) / (256 * 8)), dim3(256), 0, stream>>>(K, Kbf);
    prep_vt<<<dim3(B_ * H_ * (S_ / 64)), dim3(256), 0, stream>>>(V, VT);
    attn_fused<1><<<dim3(grid), dim3(NTH), 0, stream>>>(
        Q, K, V, scale, M, flag, Kbf, VT, outC, outA);
  } else {
    attn_fused<0><<<dim3(grid), dim3(NTH), 0, stream>>>(
        Q, K, V, scale, M, flag, Kbf, VT, outC, outA);
  }
}